// Round 15
// baseline (379.388 us; speedup 1.0000x reference)
//
#include <hip/hip_runtime.h>

#define HC 128          // H*C = output dim
#define HEADS 8
#define EDIM 16
#define NG 8
#define GEPS 1e-5f
#define LOG2E 1.44269504f

typedef float f32x2 __attribute__((ext_vector_type(2)));
typedef float f32x4m __attribute__((ext_vector_type(4)));
typedef short s16x8 __attribute__((ext_vector_type(8)));

// ---------- bf16 helpers (round-to-nearest-even) ----------
__device__ __forceinline__ ushort bf16_rne(float v) {
  unsigned u = __float_as_uint(v);
  u = (u + 0x7fffu + ((u >> 16) & 1u)) >> 16;
  return (ushort)u;
}
__device__ __forceinline__ unsigned pack_bf16x2(float a, float b) {
  return (unsigned)bf16_rne(a) | ((unsigned)bf16_rne(b) << 16);
}
__device__ __forceinline__ f32x2 unpack_bf16x2(unsigned u) {
  return (f32x2){__uint_as_float(u << 16), __uint_as_float(u & 0xffff0000u)};
}

// ---------- 8-lane (head) sum via DPP: half_mirror + quad_perm xor2/xor1 ----------
__device__ __forceinline__ float head8_sum(float p) {
  int t;
  t = __builtin_amdgcn_update_dpp(0, __float_as_int(p), 0x141, 0xF, 0xF, true); // row_half_mirror
  p += __int_as_float(t);
  t = __builtin_amdgcn_update_dpp(0, __float_as_int(p), 0x4E, 0xF, 0xF, true);  // quad_perm [2,3,0,1]
  p += __int_as_float(t);
  t = __builtin_amdgcn_update_dpp(0, __float_as_int(p), 0xB1, 0xF, 0xF, true);  // quad_perm [1,0,3,2]
  p += __int_as_float(t);
  return p;
}

// ---------- K0: zero scratch ----------
__global__ void zero_k(float* __restrict__ p, size_t nwords) {
  size_t i = (size_t)blockIdx.x * 256 + threadIdx.x;
  if (i < nwords) p[i] = 0.f;
}

// ---------- K1: degree of real edges (by dst) + group-boundary marks ----------
__global__ void count_deg_mark(const int* __restrict__ ei, int* __restrict__ deg,
                               const int* __restrict__ batch, int* __restrict__ genc,
                               int E, int N) {
  int e = blockIdx.x * 256 + threadIdx.x;
  if (e >= E) return;
  atomicAdd(&deg[ei[E + e]], 1);
  if (e < N && (e == 0 || batch[e] != batch[e - 1])) {
    // encode start index i as (N - i) so zero-init means "empty group"
    atomicMax(&genc[batch[e]], N - e);
  }
}

// ---------- K1b: WeT (attention weights transposed) + split-bf16 WbT ----------
// WeT[c][k] = We[k][c] (2048 f32). WbT[n][k] = bf16-split of (n<128?Wl:Wr)[k][n']
// (256x128, hi+lo planes). Block 0 does WeT; blocks 1..32 do WbT.
__global__ void __launch_bounds__(256) prep_w(
    const float* __restrict__ We, float* __restrict__ WeT,
    const float* __restrict__ Wl, const float* __restrict__ Wr,
    ushort* __restrict__ wth, ushort* __restrict__ wtl) {
  int b = blockIdx.x, t = threadIdx.x;
  if (b == 0) {
    #pragma unroll
    for (int i = 0; i < 8; ++i) {
      int idx = t + i * 256;          // 0..2047
      int c = idx >> 4, k = idx & 15;
      WeT[idx] = We[k * HC + c];
    }
  } else {
    int base = (b - 1) * 1024 + t * 4;
    #pragma unroll
    for (int i = 0; i < 4; ++i) {
      int idx = base + i;             // 0..32767
      int n = idx >> 7, k = idx & 127;
      float v = (n < HC) ? Wl[k * HC + n] : Wr[k * HC + (n - HC)];
      ushort h = bf16_rne(v);
      float fh = __uint_as_float(((unsigned)h) << 16);
      wth[idx] = h;
      wtl[idx] = bf16_rne(v - fh);
    }
  }
}

// ---------- K1c: split x into hi/lo bf16 planes ----------
__global__ void __launch_bounds__(256) conv_x_split(
    const float* __restrict__ x, ushort* __restrict__ xh,
    ushort* __restrict__ xlo, long total) {
  long i = ((long)blockIdx.x * 256 + threadIdx.x) * 4;
  if (i >= total) return;
  float4 a = *(const float4*)(x + i);
  ushort4 h, lo;
  #pragma unroll
  for (int k = 0; k < 4; ++k) {
    float v = (&a.x)[k];
    ushort hh = bf16_rne(v);
    float fh = __uint_as_float(((unsigned)hh) << 16);
    (&h.x)[k] = hh;
    (&lo.x)[k] = bf16_rne(v - fh);
  }
  *(ushort4*)(xh + i) = h;
  *(ushort4*)(xlo + i) = lo;
}

// ---------- K2: MFMA GEMM  [xl|xr] = x @ [Wl|Wr] + [bl|br]  (split-bf16, 3xMFMA) ----
// x·w = xh·wh + xh·wl + xl·wh (rel err ~2^-17: fp32-equivalent). Per wave: one
// 16-row M-tile x full N=256, K=128 via mfma_f32_16x16x32_bf16. Fragment
// layout (guide §3, m89/m97-verified): A lane l holds A[l&15][(l>>4)*8+j]
// contiguous-K bf16x8; B likewise from transposed WbT[n][k]; D col=l&15,
// row=(l>>4)*4+reg. Bias folded into acc init. Emits fp32 xl,xr and bf16 xlh
// (adjacent-column pack via shfl_xor). 4 independent waves per block.
__global__ void __launch_bounds__(256) gemm_mfma(
    const ushort* __restrict__ xh, const ushort* __restrict__ xlo,
    const ushort* __restrict__ wth, const ushort* __restrict__ wtl,
    const float* __restrict__ bl, const float* __restrict__ br,
    float* __restrict__ xl, float* __restrict__ xr,
    unsigned* __restrict__ xlh, int N) {
  int t = threadIdx.x;
  int l = t & 63;
  long m0 = ((long)blockIdx.x * 4 + (t >> 6)) * 16;
  if (m0 >= N) return;                 // N%16==0 for this problem; full tiles
  int lo16 = l & 15;
  int kg = l >> 4;
  s16x8 ah[4], al[4];
  #pragma unroll
  for (int ks = 0; ks < 4; ++ks) {
    long off = (m0 + lo16) * HC + ks * 32 + kg * 8;
    ah[ks] = *(const s16x8*)(xh + off);
    al[ks] = *(const s16x8*)(xlo + off);
  }
  f32x4m acc[16];
  #pragma unroll
  for (int nt = 0; nt < 16; ++nt) {
    int c = nt * 16 + lo16;
    float bv = (c < HC) ? bl[c] : br[c - HC];
    acc[nt] = (f32x4m){bv, bv, bv, bv};
  }
  #pragma unroll
  for (int nt = 0; nt < 16; ++nt) {
    #pragma unroll
    for (int ks = 0; ks < 4; ++ks) {
      long woff = (long)(nt * 16 + lo16) * HC + ks * 32 + kg * 8;
      s16x8 bh = *(const s16x8*)(wth + woff);
      s16x8 bo = *(const s16x8*)(wtl + woff);
      acc[nt] = __builtin_amdgcn_mfma_f32_16x16x32_bf16(ah[ks], bh, acc[nt], 0, 0, 0);
      acc[nt] = __builtin_amdgcn_mfma_f32_16x16x32_bf16(ah[ks], bo, acc[nt], 0, 0, 0);
      acc[nt] = __builtin_amdgcn_mfma_f32_16x16x32_bf16(al[ks], bh, acc[nt], 0, 0, 0);
    }
  }
  #pragma unroll
  for (int nt = 0; nt < 16; ++nt) {
    int c = nt * 16 + lo16;
    #pragma unroll
    for (int r = 0; r < 4; ++r) {
      long row = m0 + kg * 4 + r;
      float v = acc[nt][r];
      if (c < HC) {
        xl[row * HC + c] = v;
        float nb = __shfl_xor(v, 1);   // lane^1 holds column c^1, same row
        if (!(c & 1)) xlh[row * (HC / 2) + (c >> 1)] = pack_bf16x2(v, nb);
      } else {
        xr[row * HC + (c - HC)] = v;
      }
    }
  }
}

// ---------- K3: scan of deg -> offsets (CSR) ----------
__global__ void scan1(const int* __restrict__ deg, int* __restrict__ bsum, int N) {
  __shared__ int s[256];
  int t = threadIdx.x;
  int n = blockIdx.x * 256 + t;
  s[t] = (n < N) ? deg[n] : 0;
  __syncthreads();
  for (int off = 128; off > 0; off >>= 1) {
    if (t < off) s[t] += s[t + off];
    __syncthreads();
  }
  if (t == 0) bsum[blockIdx.x] = s[0];
}
// parallel scan of block sums (nb <= 256) + group-start decode; 1 block x 256
__global__ void scan2(const int* __restrict__ bsum, int* __restrict__ bofs, int nb,
                      int* __restrict__ offsets, int N,
                      const int* __restrict__ genc, int* __restrict__ gstart) {
  __shared__ int s[256];
  int t = threadIdx.x;
  int v = (t < nb) ? bsum[t] : 0;
  s[t] = v;
  __syncthreads();
  for (int off = 1; off < 256; off <<= 1) {
    int add = (t >= off) ? s[t - off] : 0;
    __syncthreads();
    s[t] += add;
    __syncthreads();
  }
  if (t < nb) bofs[t] = s[t] - v;        // exclusive
  if (t == 255) offsets[N] = s[255];     // total (tail lanes contribute 0)
  if (t == 0) {
    // decode group starts; suffix-min so empty groups collapse to 0-length
    int nxt = N;
    gstart[NG] = N;
    for (int g = NG - 1; g >= 0; --g) {
      int st = N - genc[g];
      if (st > nxt) st = nxt;
      gstart[g] = st;
      nxt = st;
    }
  }
}
__global__ void scan3(const int* __restrict__ deg, const int* __restrict__ bofs,
                      int* __restrict__ offsets, int N) {
  __shared__ int s[256];
  int t = threadIdx.x;
  int n = blockIdx.x * 256 + t;
  int v = (n < N) ? deg[n] : 0;
  s[t] = v;
  __syncthreads();
  for (int off = 1; off < 256; off <<= 1) {
    int add = (t >= off) ? s[t - off] : 0;
    __syncthreads();
    s[t] += add;
    __syncthreads();
  }
  if (n < N) offsets[n] = bofs[blockIdx.x] + s[t] - v;  // exclusive
}

// ---------- K4: fill CSR with (edge, src) pairs; consumes deg ----------
__global__ void fill_csr(const int* __restrict__ ei, int* __restrict__ deg,
                         const int* __restrict__ offsets, int2* __restrict__ csr2, int E) {
  int e = blockIdx.x * 256 + threadIdx.x;
  if (e >= E) return;
  int d = ei[E + e];
  int pos = atomicSub(&deg[d], 1) - 1;
  csr2[offsets[d] + pos] = make_int2(e, ei[e]);
}

// ---------- K5: FUSED per-node attention + defer-max online softmax + agg ----------
// ONE WAVE per node, ONE 64-thread BLOCK per wave, grid = N (R12/R13 lessons:
// independent 1-wave blocks avoid lifetime coupling AND let the HW scheduler
// load-balance Poisson-variable node degrees dynamically). Weight prologue
// from transposed WeT (8 float4 loads). Lane l owns channels (2l,2l+1) packed
// f32x2; neighbor xl gathered bf16 (4B/lane). Head = 8 lanes -> 3-stage DPP.
// Self-loop (ea fill 'mean') merged via linearity. Logits in log2 space.
__global__ void __launch_bounds__(64) fused_node(
    const int* __restrict__ offsets, const int2* __restrict__ csr2,
    const float* __restrict__ ea, const unsigned* __restrict__ xlh,
    const float* __restrict__ xl, const float* __restrict__ xr,
    const float* __restrict__ WeT, const float* __restrict__ att,
    const float* __restrict__ x, const float* __restrict__ bias,
    float* __restrict__ out, int N) {
  int l = threadIdx.x;
  long n = blockIdx.x;
  if (n >= N) return;
  int c0 = l * 2;
  f32x2 wx[8], wy[8];
  {
    const float4* wa = (const float4*)(WeT + c0 * EDIM);
    const float4* wb = (const float4*)(WeT + (c0 + 1) * EDIM);
    #pragma unroll
    for (int q = 0; q < 4; ++q) {
      float4 A = wa[q], B = wb[q];
      wx[2 * q]     = (f32x2){A.x, A.y};
      wx[2 * q + 1] = (f32x2){A.z, A.w};
      wy[2 * q]     = (f32x2){B.x, B.y};
      wy[2 * q + 1] = (f32x2){B.z, B.w};
    }
  }
  f32x2 av2 = {att[c0] * LOG2E, att[c0 + 1] * LOG2E};
  f32x2 av08 = 0.8f * av2, av02 = 0.2f * av2;
  f32x2 xl2 = *(const f32x2*)(xl + n * HC + c0);
  f32x2 xr2 = *(const f32x2*)(xr + n * HC + c0);
  f32x2 seedA = {xr2.x, 0.f};   // dot-accumulator seeds (fold +xr into hadd)
  f32x2 seedB = {xr2.y, 0.f};
  int j0 = offsets[n], j1 = offsets[n + 1];

  float m = -INFINITY;          // running max (log2), uniform per 8-lane head
  float den = 0.f;
  f32x2 acc = {0.f, 0.f};
  f32x2 eesum = {0.f, 0.f};     // per-channel sum of (eev + xr); adjusted at end

  auto edge_update = [&](int e, f32x2 xls) {
    const float4* eap = (const float4*)(ea + (long)e * EDIM);
    float4 a0 = eap[0], a1 = eap[1], a2 = eap[2], a3 = eap[3];
    f32x2 dA = seedA, dB = seedB;
    f32x2 e01;
    e01 = (f32x2){a0.x, a0.y};
    dA = __builtin_elementwise_fma(e01, wx[0], dA);
    dB = __builtin_elementwise_fma(e01, wy[0], dB);
    e01 = (f32x2){a0.z, a0.w};
    dA = __builtin_elementwise_fma(e01, wx[1], dA);
    dB = __builtin_elementwise_fma(e01, wy[1], dB);
    e01 = (f32x2){a1.x, a1.y};
    dA = __builtin_elementwise_fma(e01, wx[2], dA);
    dB = __builtin_elementwise_fma(e01, wy[2], dB);
    e01 = (f32x2){a1.z, a1.w};
    dA = __builtin_elementwise_fma(e01, wx[3], dA);
    dB = __builtin_elementwise_fma(e01, wy[3], dB);
    e01 = (f32x2){a2.x, a2.y};
    dA = __builtin_elementwise_fma(e01, wx[4], dA);
    dB = __builtin_elementwise_fma(e01, wy[4], dB);
    e01 = (f32x2){a2.z, a2.w};
    dA = __builtin_elementwise_fma(e01, wx[5], dA);
    dB = __builtin_elementwise_fma(e01, wy[5], dB);
    e01 = (f32x2){a3.x, a3.y};
    dA = __builtin_elementwise_fma(e01, wx[6], dA);
    dB = __builtin_elementwise_fma(e01, wy[6], dB);
    e01 = (f32x2){a3.z, a3.w};
    dA = __builtin_elementwise_fma(e01, wx[7], dA);
    dB = __builtin_elementwise_fma(e01, wy[7], dB);
    f32x2 mm = {dA.x + dA.y, dB.x + dB.y};   // = eev + xr (per channel)
    eesum += mm;
    mm += xls;
    f32x2 tt = __builtin_elementwise_fma(
        av08, __builtin_elementwise_max(mm, (f32x2)0.f), av02 * mm);
    float p = head8_sum(tt.x + tt.y);  // head logit, uniform in 8-lane group
    if (p > m + 11.5f) {               // rare: new max grew past threshold
      float sc = exp2f(m - p);
      acc = acc * sc + xls;
      den = fmaf(den, sc, 1.f);
      m = p;
    } else {                           // common: single exp2, no rescale
      float w = exp2f(p - m);
      acc = __builtin_elementwise_fma((f32x2)w, xls, acc);
      den += w;
    }
  };

  auto gath = [&](int s) -> f32x2 {
    return unpack_bf16x2(xlh[(long)s * (HC / 2) + l]);   // 4B/lane bf16 gather
  };
  auto edge_single = [&](int jj) {
    int2 es = csr2[jj];
    int e = __builtin_amdgcn_readfirstlane(es.x);
    int s = __builtin_amdgcn_readfirstlane(es.y);
    edge_update(e, gath(s));
  };

  int j = j0;
  if ((j & 1) && j < j1) { edge_single(j); ++j; }   // peel to 16B alignment
  for (; j + 1 < j1; j += 2) {
    int4 q = *(const int4*)(csr2 + j);  // two (edge,src) pairs, one dwordx4
    int e0 = __builtin_amdgcn_readfirstlane(q.x);
    int s0 = __builtin_amdgcn_readfirstlane(q.y);
    int e1 = __builtin_amdgcn_readfirstlane(q.z);
    int s1 = __builtin_amdgcn_readfirstlane(q.w);
    f32x2 xls0 = gath(s0);
    f32x2 xls1 = gath(s1);
    edge_update(e0, xls0);
    edge_update(e1, xls1);
  }
  if (j < j1) edge_single(j);

  // ---- self-loop ----
  int dg = j1 - j0;
  f32x2 ee = (dg > 0) ? (eesum * (1.f / (float)dg) - xr2) : (f32x2)0.f;
  f32x2 mm = xl2 + xr2 + ee;
  f32x2 tt = __builtin_elementwise_fma(
      av08, __builtin_elementwise_max(mm, (f32x2)0.f), av02 * mm);
  float p = head8_sum(tt.x + tt.y);
  if (p > m) {
    float sc = exp2f(m - p);
    acc = acc * sc + xl2;
    den = fmaf(den, sc, 1.f);
  } else {
    float w = exp2f(p - m);
    acc = __builtin_elementwise_fma((f32x2)w, xl2, acc);
    den += w;
  }

  f32x2 b2 = *(const f32x2*)(bias + c0);
  f32x2 x2 = *(const f32x2*)(x + n * HC + c0);
  f32x2 o = acc * (1.f / den) + b2 + x2;
  *(f32x2*)(out + n * HC + c0) = o;
}

// ---------- K6: GraphNorm segment sums (grid-parallel over group slices) ----------
#define GN_SLICES 32
__global__ void __launch_bounds__(128) gn_stats(
    const float* __restrict__ out, const int* __restrict__ gstart,
    float* __restrict__ gsum, float* __restrict__ gsq) {
  int g = blockIdx.x >> 5;
  int slice = blockIdx.x & 31;
  int s0 = gstart[g], s1 = gstart[g + 1];
  int cnt = s1 - s0;
  if (cnt <= 0) return;
  int chunk = (cnt + GN_SLICES - 1) / GN_SLICES;
  int lo = s0 + slice * chunk;
  int hi = lo + chunk; if (hi > s1) hi = s1;
  if (lo >= hi) return;
  int ch = threadIdx.x;
  float sum = 0.f, sq = 0.f;
  for (int nrow = lo; nrow < hi; ++nrow) {
    float v = out[(long)nrow * HC + ch];
    sum += v; sq += v * v;
  }
  atomicAdd(&gsum[g * HC + ch], sum);
  atomicAdd(&gsq[g * HC + ch], sq);
}

// ---------- K7: normalize + affine + ELU, with inline mean/istd (fused finalize) ----
__global__ void gn_apply(float* __restrict__ out, const int* __restrict__ batch,
                         const float* __restrict__ gsum, const float* __restrict__ gsq,
                         const int* __restrict__ gstart, const float* __restrict__ gms,
                         const float* __restrict__ gnw, const float* __restrict__ gnb, int N) {
  long i = (long)blockIdx.x * 256 + threadIdx.x;     // float4 index
  if (i >= (long)N * 32) return;
  int c4 = (int)(i & 31);
  long n = i >> 5;
  int g = batch[n];
  float cnt = (float)(gstart[g + 1] - gstart[g]);
  if (cnt < 1.f) cnt = 1.f;
  float ic = 1.f / cnt;
  float4 su = ((const float4*)gsum)[g * 32 + c4];
  float4 sq = ((const float4*)gsq)[g * 32 + c4];
  float4 ms4 = ((const float4*)gms)[c4];
  float4 v = ((const float4*)out)[i];
  float4 w  = ((const float4*)gnw)[c4];
  float4 b  = ((const float4*)gnb)[c4];
  float4 o;
  #pragma unroll
  for (int k = 0; k < 4; ++k) {
    float mean = (&su.x)[k] * ic;
    float c = (&ms4.x)[k] * mean;                       // subtracted constant
    float var = (&sq.x)[k] * ic - 2.f * c * mean + c * c;
    float istd = rsqrtf(var + GEPS);
    float oo = fmaf((&w.x)[k] * ((&v.x)[k] - c), istd, (&b.x)[k]);
    (&o.x)[k] = oo > 0.f ? oo : expm1f(oo);
  }
  ((float4*)out)[i] = o;
}

extern "C" void kernel_launch(void* const* d_in, const int* in_sizes, int n_in,
                              void* d_out, int out_size, void* d_ws, size_t ws_size,
                              hipStream_t stream) {
  const float* x    = (const float*)d_in[0];
  const int*   ei   = (const int*)d_in[1];
  const float* ea   = (const float*)d_in[2];
  const int*   batch= (const int*)d_in[3];
  const float* Wl   = (const float*)d_in[4];
  const float* bl   = (const float*)d_in[5];
  const float* Wr   = (const float*)d_in[6];
  const float* br   = (const float*)d_in[7];
  const float* We   = (const float*)d_in[8];
  const float* att  = (const float*)d_in[9];
  const float* bias = (const float*)d_in[10];
  const float* gnw  = (const float*)d_in[11];
  const float* gnb  = (const float*)d_in[12];
  const float* gms  = (const float*)d_in[13];
  int N = in_sizes[0] / HC;
  int E = in_sizes[2] / EDIM;
  float* out = (float*)d_out;
  (void)n_in; (void)out_size; (void)ws_size;

  // ---- workspace carve-up (4-byte words, 16B aligned blocks) ----
  float* wsf = (float*)d_ws;
  size_t off = 0;
  auto alloc = [&](size_t words) -> float* {
    float* p = wsf + off;
    off += (words + 3) & ~(size_t)3;
    return p;
  };
  int*      deg     = (int*)alloc(N);
  float*    gsum    = alloc(NG * HC);
  float*    gsq     = alloc(NG * HC);
  int*      genc    = (int*)alloc(NG);
  size_t zero_words = off;                 // everything above starts at 0
  int*      gstart  = (int*)alloc(NG + 1);
  int*      bsum    = (int*)alloc(256);
  int*      bofs    = (int*)alloc(256);
  float*    WeT     = alloc(HC * EDIM);
  ushort*   wth     = (ushort*)alloc(256 * HC / 2);
  ushort*   wtl     = (ushort*)alloc(256 * HC / 2);
  int*      offsets = (int*)alloc((size_t)N + 1);
  float*    xl      = alloc((size_t)N * HC);
  float*    xr      = alloc((size_t)N * HC);
  unsigned* xlh     = (unsigned*)alloc((size_t)N * (HC / 2));
  ushort*   xbh     = (ushort*)alloc((size_t)N * (HC / 2));
  ushort*   xbl     = (ushort*)alloc((size_t)N * (HC / 2));
  int2*     csr2    = (int2*)alloc((size_t)E * 2 + 8);

  int nb = (N + 255) / 256;   // scan blocks (<=256 by construction for N<=65536)

  zero_k<<<(unsigned)((zero_words + 255) / 256), 256, 0, stream>>>(wsf, zero_words);
  count_deg_mark<<<(E + 255) / 256, 256, 0, stream>>>(ei, deg, batch, genc, E, N);
  prep_w<<<33, 256, 0, stream>>>(We, WeT, Wl, Wr, wth, wtl);
  {
    long total = (long)N * HC;
    conv_x_split<<<(unsigned)((total / 4 + 255) / 256), 256, 0, stream>>>(x, xbh, xbl, total);
  }
  {
    int mtiles = (N + 15) / 16;
    gemm_mfma<<<(mtiles + 3) / 4, 256, 0, stream>>>(xbh, xbl, wth, wtl, bl, br, xl, xr, xlh, N);
  }
  scan1<<<nb, 256, 0, stream>>>(deg, bsum, N);
  scan2<<<1, 256, 0, stream>>>(bsum, bofs, nb, offsets, N, genc, gstart);
  scan3<<<nb, 256, 0, stream>>>(deg, bofs, offsets, N);
  fill_csr<<<(E + 255) / 256, 256, 0, stream>>>(ei, deg, offsets, csr2, E);
  fused_node<<<N, 64, 0, stream>>>(offsets, csr2, ea, xlh, xl, xr, WeT, att, x, bias, out, N);
  gn_stats<<<NG * GN_SLICES, 128, 0, stream>>>(out, gstart, gsum, gsq);
  {
    long tot = (long)N * 32;
    gn_apply<<<(unsigned)((tot + 255) / 256), 256, 0, stream>>>(out, batch, gsum, gsq, gstart, gms, gnw, gnb, N);
  }
}

// Round 16
// 328.695 us; speedup vs baseline: 1.1542x; 1.1542x over previous
//
#include <hip/hip_runtime.h>

#define HC 128          // H*C = output dim
#define HEADS 8
#define EDIM 16
#define NG 8
#define GEPS 1e-5f
#define LOG2E 1.44269504f

typedef float f32x2 __attribute__((ext_vector_type(2)));

// ---------- bf16x2 pack/unpack (round-to-nearest-even) ----------
__device__ __forceinline__ unsigned pack_bf16x2(float a, float b) {
  unsigned ua = __float_as_uint(a), ub = __float_as_uint(b);
  ua = (ua + 0x7fffu + ((ua >> 16) & 1u)) >> 16;
  ub = (ub + 0x7fffu + ((ub >> 16) & 1u)) >> 16;
  return ua | (ub << 16);
}
__device__ __forceinline__ f32x2 unpack_bf16x2(unsigned u) {
  return (f32x2){__uint_as_float(u << 16), __uint_as_float(u & 0xffff0000u)};
}

// ---------- 8-lane (head) sum via DPP: half_mirror + quad_perm xor2/xor1 ----------
__device__ __forceinline__ float head8_sum(float p) {
  int t;
  t = __builtin_amdgcn_update_dpp(0, __float_as_int(p), 0x141, 0xF, 0xF, true); // row_half_mirror
  p += __int_as_float(t);
  t = __builtin_amdgcn_update_dpp(0, __float_as_int(p), 0x4E, 0xF, 0xF, true);  // quad_perm [2,3,0,1]
  p += __int_as_float(t);
  t = __builtin_amdgcn_update_dpp(0, __float_as_int(p), 0xB1, 0xF, 0xF, true);  // quad_perm [1,0,3,2]
  p += __int_as_float(t);
  return p;
}

// ---------- K0: zero scratch ----------
__global__ void zero_k(float* __restrict__ p, size_t nwords) {
  size_t i = (size_t)blockIdx.x * 256 + threadIdx.x;
  if (i < nwords) p[i] = 0.f;
}

// ---------- K1: MERGED phase1 -- GEMM role + edge-count role ----------
// Blocks [0, nbG): LDS-tiled GEMM  xr = x@Wr+br (fp32), xlh = bf16(x@Wl+bl).
// Blocks [nbG, nbG+nbC): degree count + group-boundary marks (independent of
// GEMM; merged so the ~15us of random atomics hides under the GEMM's compute
// -- same-stream kernels otherwise serialize). zero_k must run before (deg/genc).
// fp32 xl eliminated entirely: its only consumer (fused_node self-loop) now
// uses the bf16 xlh row, matching the neighbors' precision treatment.
#define GEMM_ROWS 32
__global__ void __launch_bounds__(256) phase1(
    const float* __restrict__ x,
    const float* __restrict__ Wl, const float* __restrict__ bl,
    const float* __restrict__ Wr, const float* __restrict__ br,
    float* __restrict__ xr, unsigned* __restrict__ xlh,
    const int* __restrict__ ei, int* __restrict__ deg,
    const int* __restrict__ batch, int* __restrict__ genc,
    int nbG, int E, int N) {
  __shared__ float4 WL[32][32];   // [k within chunk][col float4 group] 16KB
  __shared__ float4 WR[32][32];   // 16KB
  __shared__ float4 XS[GEMM_ROWS][8];  // [local row][k4 within chunk] 4KB
  int b = blockIdx.x;
  int t = threadIdx.x;
  if (b >= nbG) {
    // ---- edge-count role ----
    int e = (b - nbG) * 256 + t;
    if (e >= E) return;
    atomicAdd(&deg[ei[E + e]], 1);
    if (e < N && (e == 0 || batch[e] != batch[e - 1])) {
      // encode start index i as (N - i) so zero-init means "empty group"
      atomicMax(&genc[batch[e]], N - e);
    }
    return;
  }
  // ---- GEMM role ----
  int cg = t & 31;                // col float4 group (0..31)
  int rt = t >> 5;                // row-thread (0..7), owns rows rt*4..rt*4+3
  int row0 = b * GEMM_ROWS;
  float4 bl4 = ((const float4*)bl)[cg];
  float4 br4 = ((const float4*)br)[cg];
  float4 accl[4], accr[4];
  #pragma unroll
  for (int r = 0; r < 4; ++r) { accl[r] = bl4; accr[r] = br4; }
  const float4* Wl4 = (const float4*)Wl;
  const float4* Wr4 = (const float4*)Wr;
  const float4* x4  = (const float4*)x;
  int srow = t >> 3, sk4 = t & 7;
  long sgrow = row0 + srow;
  for (int kc = 0; kc < 4; ++kc) {
    __syncthreads();              // previous chunk fully consumed
    #pragma unroll
    for (int i = 0; i < 4; ++i) {
      int idx = t + i * 256;      // 0..1023
      int kr = idx >> 5, gg = idx & 31;
      WL[kr][gg] = Wl4[(kc * 32 + kr) * 32 + gg];
      WR[kr][gg] = Wr4[(kc * 32 + kr) * 32 + gg];
    }
    XS[srow][sk4] = (sgrow < N) ? x4[sgrow * 32 + kc * 8 + sk4]
                                : make_float4(0.f, 0.f, 0.f, 0.f);
    __syncthreads();
    #pragma unroll
    for (int k4 = 0; k4 < 8; ++k4) {
      float4 xv[4];
      #pragma unroll
      for (int r = 0; r < 4; ++r) xv[r] = XS[rt * 4 + r][k4];
      #pragma unroll
      for (int kk = 0; kk < 4; ++kk) {
        float4 wl = WL[k4 * 4 + kk][cg];
        float4 wr = WR[k4 * 4 + kk][cg];
        #pragma unroll
        for (int r = 0; r < 4; ++r) {
          float xs = (&xv[r].x)[kk];
          accl[r].x = fmaf(xs, wl.x, accl[r].x);
          accl[r].y = fmaf(xs, wl.y, accl[r].y);
          accl[r].z = fmaf(xs, wl.z, accl[r].z);
          accl[r].w = fmaf(xs, wl.w, accl[r].w);
          accr[r].x = fmaf(xs, wr.x, accr[r].x);
          accr[r].y = fmaf(xs, wr.y, accr[r].y);
          accr[r].z = fmaf(xs, wr.z, accr[r].z);
          accr[r].w = fmaf(xs, wr.w, accr[r].w);
        }
      }
    }
  }
  #pragma unroll
  for (int r = 0; r < 4; ++r) {
    long row = row0 + rt * 4 + r;
    if (row < N) {
      ((float4*)(xr + row * HC))[cg] = accr[r];
      uint2 h;
      h.x = pack_bf16x2(accl[r].x, accl[r].y);
      h.y = pack_bf16x2(accl[r].z, accl[r].w);
      ((uint2*)(xlh + row * (HC / 2)))[cg] = h;
    }
  }
}

// ---------- K3: scan of deg -> offsets (CSR) ----------
__global__ void scan1(const int* __restrict__ deg, int* __restrict__ bsum, int N) {
  __shared__ int s[256];
  int t = threadIdx.x;
  int n = blockIdx.x * 256 + t;
  s[t] = (n < N) ? deg[n] : 0;
  __syncthreads();
  for (int off = 128; off > 0; off >>= 1) {
    if (t < off) s[t] += s[t + off];
    __syncthreads();
  }
  if (t == 0) bsum[blockIdx.x] = s[0];
}
// parallel scan of block sums (nb <= 256) + group-start decode; 1 block x 256
__global__ void scan2(const int* __restrict__ bsum, int* __restrict__ bofs, int nb,
                      int* __restrict__ offsets, int N,
                      const int* __restrict__ genc, int* __restrict__ gstart) {
  __shared__ int s[256];
  int t = threadIdx.x;
  int v = (t < nb) ? bsum[t] : 0;
  s[t] = v;
  __syncthreads();
  for (int off = 1; off < 256; off <<= 1) {
    int add = (t >= off) ? s[t - off] : 0;
    __syncthreads();
    s[t] += add;
    __syncthreads();
  }
  if (t < nb) bofs[t] = s[t] - v;        // exclusive
  if (t == 255) offsets[N] = s[255];     // total (tail lanes contribute 0)
  if (t == 0) {
    // decode group starts; suffix-min so empty groups collapse to 0-length
    int nxt = N;
    gstart[NG] = N;
    for (int g = NG - 1; g >= 0; --g) {
      int st = N - genc[g];
      if (st > nxt) st = nxt;
      gstart[g] = st;
      nxt = st;
    }
  }
}
__global__ void scan3(const int* __restrict__ deg, const int* __restrict__ bofs,
                      int* __restrict__ offsets, int N) {
  __shared__ int s[256];
  int t = threadIdx.x;
  int n = blockIdx.x * 256 + t;
  int v = (n < N) ? deg[n] : 0;
  s[t] = v;
  __syncthreads();
  for (int off = 1; off < 256; off <<= 1) {
    int add = (t >= off) ? s[t - off] : 0;
    __syncthreads();
    s[t] += add;
    __syncthreads();
  }
  if (n < N) offsets[n] = bofs[blockIdx.x] + s[t] - v;  // exclusive
}

// ---------- K4: fill CSR with (edge, src) pairs; consumes deg ----------
__global__ void fill_csr(const int* __restrict__ ei, int* __restrict__ deg,
                         const int* __restrict__ offsets, int2* __restrict__ csr2, int E) {
  int e = blockIdx.x * 256 + threadIdx.x;
  if (e >= E) return;
  int d = ei[E + e];
  int pos = atomicSub(&deg[d], 1) - 1;
  csr2[offsets[d] + pos] = make_int2(e, ei[e]);
}

// ---------- K5: FUSED per-node attention + defer-max online softmax + agg ----------
// ONE WAVE per node, ONE 64-thread BLOCK per wave, grid = N (R12/R13 lessons:
// independent 1-wave blocks avoid lifetime coupling AND let the HW scheduler
// load-balance Poisson-variable node degrees dynamically). Lane l owns channels
// (2l,2l+1) packed f32x2; neighbor AND self-loop xl in bf16 from xlh (4B/lane).
// Head = 8 lanes -> 3-stage DPP. Self-loop (ea fill 'mean') merged via
// linearity. Logits in log2 space (att pre-scaled by log2e).
__global__ void __launch_bounds__(64) fused_node(
    const int* __restrict__ offsets, const int2* __restrict__ csr2,
    const float* __restrict__ ea, const unsigned* __restrict__ xlh,
    const float* __restrict__ xr,
    const float* __restrict__ We, const float* __restrict__ att,
    const float* __restrict__ x, const float* __restrict__ bias,
    float* __restrict__ out, int N) {
  int l = threadIdx.x;
  long n = blockIdx.x;
  if (n >= N) return;
  int c0 = l * 2;
  // We pairs, k-major: wx[kp] = (We[2kp][c0], We[2kp+1][c0]); wy for c0+1.
  f32x2 wx[8], wy[8];
  #pragma unroll
  for (int kp = 0; kp < 8; ++kp) {
    wx[kp] = (f32x2){We[(2 * kp) * HC + c0],     We[(2 * kp + 1) * HC + c0]};
    wy[kp] = (f32x2){We[(2 * kp) * HC + c0 + 1], We[(2 * kp + 1) * HC + c0 + 1]};
  }
  f32x2 av2 = {att[c0] * LOG2E, att[c0 + 1] * LOG2E};
  f32x2 av08 = 0.8f * av2, av02 = 0.2f * av2;
  f32x2 xl2 = unpack_bf16x2(xlh[n * (HC / 2) + l]);   // self-loop xl (bf16)
  f32x2 xr2 = *(const f32x2*)(xr + n * HC + c0);
  f32x2 seedA = {xr2.x, 0.f};   // dot-accumulator seeds (fold +xr into hadd)
  f32x2 seedB = {xr2.y, 0.f};
  int j0 = offsets[n], j1 = offsets[n + 1];

  float m = -INFINITY;          // running max (log2), uniform per 8-lane head
  float den = 0.f;
  f32x2 acc = {0.f, 0.f};
  f32x2 eesum = {0.f, 0.f};     // per-channel sum of (eev + xr); adjusted at end

  auto edge_update = [&](int e, f32x2 xls) {
    const float4* eap = (const float4*)(ea + (long)e * EDIM);
    float4 a0 = eap[0], a1 = eap[1], a2 = eap[2], a3 = eap[3];
    f32x2 dA = seedA, dB = seedB;
    f32x2 e01;
    e01 = (f32x2){a0.x, a0.y};
    dA = __builtin_elementwise_fma(e01, wx[0], dA);
    dB = __builtin_elementwise_fma(e01, wy[0], dB);
    e01 = (f32x2){a0.z, a0.w};
    dA = __builtin_elementwise_fma(e01, wx[1], dA);
    dB = __builtin_elementwise_fma(e01, wy[1], dB);
    e01 = (f32x2){a1.x, a1.y};
    dA = __builtin_elementwise_fma(e01, wx[2], dA);
    dB = __builtin_elementwise_fma(e01, wy[2], dB);
    e01 = (f32x2){a1.z, a1.w};
    dA = __builtin_elementwise_fma(e01, wx[3], dA);
    dB = __builtin_elementwise_fma(e01, wy[3], dB);
    e01 = (f32x2){a2.x, a2.y};
    dA = __builtin_elementwise_fma(e01, wx[4], dA);
    dB = __builtin_elementwise_fma(e01, wy[4], dB);
    e01 = (f32x2){a2.z, a2.w};
    dA = __builtin_elementwise_fma(e01, wx[5], dA);
    dB = __builtin_elementwise_fma(e01, wy[5], dB);
    e01 = (f32x2){a3.x, a3.y};
    dA = __builtin_elementwise_fma(e01, wx[6], dA);
    dB = __builtin_elementwise_fma(e01, wy[6], dB);
    e01 = (f32x2){a3.z, a3.w};
    dA = __builtin_elementwise_fma(e01, wx[7], dA);
    dB = __builtin_elementwise_fma(e01, wy[7], dB);
    f32x2 mm = {dA.x + dA.y, dB.x + dB.y};   // = eev + xr (per channel)
    eesum += mm;
    mm += xls;
    f32x2 tt = __builtin_elementwise_fma(
        av08, __builtin_elementwise_max(mm, (f32x2)0.f), av02 * mm);
    float p = head8_sum(tt.x + tt.y);  // head logit, uniform in 8-lane group
    if (p > m + 11.5f) {               // rare: new max grew past threshold
      float sc = exp2f(m - p);
      acc = acc * sc + xls;
      den = fmaf(den, sc, 1.f);
      m = p;
    } else {                           // common: single exp2, no rescale
      float w = exp2f(p - m);
      acc = __builtin_elementwise_fma((f32x2)w, xls, acc);
      den += w;
    }
  };

  auto gath = [&](int s) -> f32x2 {
    return unpack_bf16x2(xlh[(long)s * (HC / 2) + l]);   // 4B/lane bf16 gather
  };
  auto edge_single = [&](int jj) {
    int2 es = csr2[jj];
    int e = __builtin_amdgcn_readfirstlane(es.x);
    int s = __builtin_amdgcn_readfirstlane(es.y);
    edge_update(e, gath(s));
  };

  int j = j0;
  if ((j & 1) && j < j1) { edge_single(j); ++j; }   // peel to 16B alignment
  for (; j + 1 < j1; j += 2) {
    int4 q = *(const int4*)(csr2 + j);  // two (edge,src) pairs, one dwordx4
    int e0 = __builtin_amdgcn_readfirstlane(q.x);
    int s0 = __builtin_amdgcn_readfirstlane(q.y);
    int e1 = __builtin_amdgcn_readfirstlane(q.z);
    int s1 = __builtin_amdgcn_readfirstlane(q.w);
    f32x2 xls0 = gath(s0);
    f32x2 xls1 = gath(s1);
    edge_update(e0, xls0);
    edge_update(e1, xls1);
  }
  if (j < j1) edge_single(j);

  // ---- self-loop ----
  int dg = j1 - j0;
  f32x2 ee = (dg > 0) ? (eesum * (1.f / (float)dg) - xr2) : (f32x2)0.f;
  f32x2 mm = xl2 + xr2 + ee;
  f32x2 tt = __builtin_elementwise_fma(
      av08, __builtin_elementwise_max(mm, (f32x2)0.f), av02 * mm);
  float p = head8_sum(tt.x + tt.y);
  if (p > m) {
    float sc = exp2f(m - p);
    acc = acc * sc + xl2;
    den = fmaf(den, sc, 1.f);
  } else {
    float w = exp2f(p - m);
    acc = __builtin_elementwise_fma((f32x2)w, xl2, acc);
    den += w;
  }

  f32x2 b2 = *(const f32x2*)(bias + c0);
  f32x2 x2 = *(const f32x2*)(x + n * HC + c0);
  f32x2 o = acc * (1.f / den) + b2 + x2;
  *(f32x2*)(out + n * HC + c0) = o;
}

// ---------- K6: GraphNorm segment sums (grid-parallel over group slices) ----------
#define GN_SLICES 32
__global__ void __launch_bounds__(128) gn_stats(
    const float* __restrict__ out, const int* __restrict__ gstart,
    float* __restrict__ gsum, float* __restrict__ gsq) {
  int g = blockIdx.x >> 5;
  int slice = blockIdx.x & 31;
  int s0 = gstart[g], s1 = gstart[g + 1];
  int cnt = s1 - s0;
  if (cnt <= 0) return;
  int chunk = (cnt + GN_SLICES - 1) / GN_SLICES;
  int lo = s0 + slice * chunk;
  int hi = lo + chunk; if (hi > s1) hi = s1;
  if (lo >= hi) return;
  int ch = threadIdx.x;
  float sum = 0.f, sq = 0.f;
  for (int nrow = lo; nrow < hi; ++nrow) {
    float v = out[(long)nrow * HC + ch];
    sum += v; sq += v * v;
  }
  atomicAdd(&gsum[g * HC + ch], sum);
  atomicAdd(&gsq[g * HC + ch], sq);
}

// ---------- K7: normalize + affine + ELU, with inline mean/istd (fused finalize) ----
__global__ void gn_apply(float* __restrict__ out, const int* __restrict__ batch,
                         const float* __restrict__ gsum, const float* __restrict__ gsq,
                         const int* __restrict__ gstart, const float* __restrict__ gms,
                         const float* __restrict__ gnw, const float* __restrict__ gnb, int N) {
  long i = (long)blockIdx.x * 256 + threadIdx.x;     // float4 index
  if (i >= (long)N * 32) return;
  int c4 = (int)(i & 31);
  long n = i >> 5;
  int g = batch[n];
  float cnt = (float)(gstart[g + 1] - gstart[g]);
  if (cnt < 1.f) cnt = 1.f;
  float ic = 1.f / cnt;
  float4 su = ((const float4*)gsum)[g * 32 + c4];
  float4 sq = ((const float4*)gsq)[g * 32 + c4];
  float4 ms4 = ((const float4*)gms)[c4];
  float4 v = ((const float4*)out)[i];
  float4 w  = ((const float4*)gnw)[c4];
  float4 b  = ((const float4*)gnb)[c4];
  float4 o;
  #pragma unroll
  for (int k = 0; k < 4; ++k) {
    float mean = (&su.x)[k] * ic;
    float c = (&ms4.x)[k] * mean;                       // subtracted constant
    float var = (&sq.x)[k] * ic - 2.f * c * mean + c * c;
    float istd = rsqrtf(var + GEPS);
    float oo = fmaf((&w.x)[k] * ((&v.x)[k] - c), istd, (&b.x)[k]);
    (&o.x)[k] = oo > 0.f ? oo : expm1f(oo);
  }
  ((float4*)out)[i] = o;
}

extern "C" void kernel_launch(void* const* d_in, const int* in_sizes, int n_in,
                              void* d_out, int out_size, void* d_ws, size_t ws_size,
                              hipStream_t stream) {
  const float* x    = (const float*)d_in[0];
  const int*   ei   = (const int*)d_in[1];
  const float* ea   = (const float*)d_in[2];
  const int*   batch= (const int*)d_in[3];
  const float* Wl   = (const float*)d_in[4];
  const float* bl   = (const float*)d_in[5];
  const float* Wr   = (const float*)d_in[6];
  const float* br   = (const float*)d_in[7];
  const float* We   = (const float*)d_in[8];
  const float* att  = (const float*)d_in[9];
  const float* bias = (const float*)d_in[10];
  const float* gnw  = (const float*)d_in[11];
  const float* gnb  = (const float*)d_in[12];
  const float* gms  = (const float*)d_in[13];
  int N = in_sizes[0] / HC;
  int E = in_sizes[2] / EDIM;
  float* out = (float*)d_out;
  (void)n_in; (void)out_size; (void)ws_size;

  // ---- workspace carve-up (4-byte words, 16B aligned blocks) ----
  float* wsf = (float*)d_ws;
  size_t off = 0;
  auto alloc = [&](size_t words) -> float* {
    float* p = wsf + off;
    off += (words + 3) & ~(size_t)3;
    return p;
  };
  int*      deg     = (int*)alloc(N);
  float*    gsum    = alloc(NG * HC);
  float*    gsq     = alloc(NG * HC);
  int*      genc    = (int*)alloc(NG);
  size_t zero_words = off;                 // everything above starts at 0
  int*      gstart  = (int*)alloc(NG + 1);
  int*      bsum    = (int*)alloc(256);
  int*      bofs    = (int*)alloc(256);
  int*      offsets = (int*)alloc((size_t)N + 1);
  float*    xr      = alloc((size_t)N * HC);
  unsigned* xlh     = (unsigned*)alloc((size_t)N * (HC / 2));
  int2*     csr2    = (int2*)alloc((size_t)E * 2 + 8);

  int nb = (N + 255) / 256;   // scan blocks (<=256 by construction for N<=65536)
  int nbG = (N + GEMM_ROWS - 1) / GEMM_ROWS;
  int nbC = (E + 255) / 256;

  zero_k<<<(unsigned)((zero_words + 255) / 256), 256, 0, stream>>>(wsf, zero_words);
  phase1<<<nbG + nbC, 256, 0, stream>>>(x, Wl, bl, Wr, br, xr, xlh,
                                        ei, deg, batch, genc, nbG, E, N);
  scan1<<<nb, 256, 0, stream>>>(deg, bsum, N);
  scan2<<<1, 256, 0, stream>>>(bsum, bofs, nb, offsets, N, genc, gstart);
  scan3<<<nb, 256, 0, stream>>>(deg, bofs, offsets, N);
  fill_csr<<<(E + 255) / 256, 256, 0, stream>>>(ei, deg, offsets, csr2, E);
  fused_node<<<N, 64, 0, stream>>>(offsets, csr2, ea, xlh, xr, We, att, x, bias, out, N);
  gn_stats<<<NG * GN_SLICES, 128, 0, stream>>>(out, gstart, gsum, gsq);
  {
    long tot = (long)N * 32;
    gn_apply<<<(unsigned)((tot + 255) / 256), 256, 0, stream>>>(out, batch, gsum, gsq, gstart, gms, gnw, gnb, N);
  }
}

// Round 17
// 319.955 us; speedup vs baseline: 1.1858x; 1.0273x over previous
//
#include <hip/hip_runtime.h>

#define HC 128          // H*C = output dim
#define HEADS 8
#define EDIM 16
#define NG 8
#define GEPS 1e-5f
#define LOG2E 1.44269504f

typedef float f32x2 __attribute__((ext_vector_type(2)));

// ---------- bf16x2 pack/unpack (round-to-nearest-even) ----------
__device__ __forceinline__ unsigned pack_bf16x2(float a, float b) {
  unsigned ua = __float_as_uint(a), ub = __float_as_uint(b);
  ua = (ua + 0x7fffu + ((ua >> 16) & 1u)) >> 16;
  ub = (ub + 0x7fffu + ((ub >> 16) & 1u)) >> 16;
  return ua | (ub << 16);
}
__device__ __forceinline__ f32x2 unpack_bf16x2(unsigned u) {
  return (f32x2){__uint_as_float(u << 16), __uint_as_float(u & 0xffff0000u)};
}

// ---------- 8-lane (head) sum via DPP: half_mirror + quad_perm xor2/xor1 ----------
__device__ __forceinline__ float head8_sum(float p) {
  int t;
  t = __builtin_amdgcn_update_dpp(0, __float_as_int(p), 0x141, 0xF, 0xF, true); // row_half_mirror
  p += __int_as_float(t);
  t = __builtin_amdgcn_update_dpp(0, __float_as_int(p), 0x4E, 0xF, 0xF, true);  // quad_perm [2,3,0,1]
  p += __int_as_float(t);
  t = __builtin_amdgcn_update_dpp(0, __float_as_int(p), 0xB1, 0xF, 0xF, true);  // quad_perm [1,0,3,2]
  p += __int_as_float(t);
  return p;
}

// ---------- K0: zero scratch ----------
__global__ void zero_k(float* __restrict__ p, size_t nwords) {
  size_t i = (size_t)blockIdx.x * 256 + threadIdx.x;
  if (i < nwords) p[i] = 0.f;
}

// ---------- K1: MERGED phase1 -- GEMM role + edge-count role ----------
// Blocks [0, nbG): LDS-tiled GEMM  xr = x@Wr+br (fp32), xlh = bf16(x@Wl+bl).
// 64 rows/block, 8 rows/thread (R16 model: GEMM is ds_read-bound, 384 b128/thr;
// 8-row tile amortizes W reads over 2x rows -> 1.6M total wave-reads, ~-16us.
// R5's spill was from in-loop GLOBAL loads, not tile size: with XS in LDS this
// is ~120 VGPR). Blocks [nbG, nbG+nbC): degree count + group-boundary marks,
// hidden under the GEMM (independent work; zero_k must precede).
#define GEMM_ROWS 64
__global__ void __launch_bounds__(256) phase1(
    const float* __restrict__ x,
    const float* __restrict__ Wl, const float* __restrict__ bl,
    const float* __restrict__ Wr, const float* __restrict__ br,
    float* __restrict__ xr, unsigned* __restrict__ xlh,
    const int* __restrict__ ei, int* __restrict__ deg,
    const int* __restrict__ batch, int* __restrict__ genc,
    int nbG, int E, int N) {
  __shared__ float4 WL[32][32];        // [k within chunk][col float4 group] 16KB
  __shared__ float4 WR[32][32];        // 16KB
  __shared__ float4 XS[GEMM_ROWS][8];  // [local row][k4 within chunk] 8KB
  int b = blockIdx.x;
  int t = threadIdx.x;
  if (b >= nbG) {
    // ---- edge-count role ----
    int e = (b - nbG) * 256 + t;
    if (e >= E) return;
    atomicAdd(&deg[ei[E + e]], 1);
    if (e < N && (e == 0 || batch[e] != batch[e - 1])) {
      // encode start index i as (N - i) so zero-init means "empty group"
      atomicMax(&genc[batch[e]], N - e);
    }
    return;
  }
  // ---- GEMM role ----
  int cg = t & 31;                // col float4 group (0..31)
  int rt = t >> 5;                // row-thread (0..7), owns rows rt*8..rt*8+7
  int row0 = b * GEMM_ROWS;
  float4 bl4 = ((const float4*)bl)[cg];
  float4 br4 = ((const float4*)br)[cg];
  float4 accl[8], accr[8];
  #pragma unroll
  for (int r = 0; r < 8; ++r) { accl[r] = bl4; accr[r] = br4; }
  const float4* Wl4 = (const float4*)Wl;
  const float4* Wr4 = (const float4*)Wr;
  const float4* x4  = (const float4*)x;
  for (int kc = 0; kc < 4; ++kc) {
    __syncthreads();              // previous chunk fully consumed
    #pragma unroll
    for (int i = 0; i < 4; ++i) {
      int idx = t + i * 256;      // 0..1023
      int kr = idx >> 5, gg = idx & 31;
      WL[kr][gg] = Wl4[(kc * 32 + kr) * 32 + gg];
      WR[kr][gg] = Wr4[(kc * 32 + kr) * 32 + gg];
    }
    #pragma unroll
    for (int i = 0; i < 2; ++i) {
      int idx = t + i * 256;      // 0..511: 64 rows x 8 k4
      int srow = idx >> 3, sk4 = idx & 7;
      long sgrow = row0 + srow;
      XS[srow][sk4] = (sgrow < N) ? x4[sgrow * 32 + kc * 8 + sk4]
                                  : make_float4(0.f, 0.f, 0.f, 0.f);
    }
    __syncthreads();
    #pragma unroll
    for (int k4 = 0; k4 < 8; ++k4) {
      float4 xv[8];
      #pragma unroll
      for (int r = 0; r < 8; ++r) xv[r] = XS[rt * 8 + r][k4];
      #pragma unroll
      for (int kk = 0; kk < 4; ++kk) {
        float4 wl = WL[k4 * 4 + kk][cg];
        float4 wr = WR[k4 * 4 + kk][cg];
        #pragma unroll
        for (int r = 0; r < 8; ++r) {
          float xs = (&xv[r].x)[kk];
          accl[r].x = fmaf(xs, wl.x, accl[r].x);
          accl[r].y = fmaf(xs, wl.y, accl[r].y);
          accl[r].z = fmaf(xs, wl.z, accl[r].z);
          accl[r].w = fmaf(xs, wl.w, accl[r].w);
          accr[r].x = fmaf(xs, wr.x, accr[r].x);
          accr[r].y = fmaf(xs, wr.y, accr[r].y);
          accr[r].z = fmaf(xs, wr.z, accr[r].z);
          accr[r].w = fmaf(xs, wr.w, accr[r].w);
        }
      }
    }
  }
  #pragma unroll
  for (int r = 0; r < 8; ++r) {
    long row = row0 + rt * 8 + r;
    if (row < N) {
      ((float4*)(xr + row * HC))[cg] = accr[r];
      uint2 h;
      h.x = pack_bf16x2(accl[r].x, accl[r].y);
      h.y = pack_bf16x2(accl[r].z, accl[r].w);
      ((uint2*)(xlh + row * (HC / 2)))[cg] = h;
    }
  }
}

// ---------- K2: per-block sums of deg ----------
__global__ void scan1(const int* __restrict__ deg, int* __restrict__ bsum, int N) {
  __shared__ int s[256];
  int t = threadIdx.x;
  int n = blockIdx.x * 256 + t;
  s[t] = (n < N) ? deg[n] : 0;
  __syncthreads();
  for (int off = 128; off > 0; off >>= 1) {
    if (t < off) s[t] += s[t + off];
    __syncthreads();
  }
  if (t == 0) bsum[blockIdx.x] = s[0];
}

// ---------- K3: MERGED scan2+scan3 -- each block self-computes its prefix ----------
// Block b sums bsum[0..b-1] cooperatively (nb<=256 ints -- trivial), then does
// its local exclusive scan of deg into offsets. No serialized 1-block pass, no
// cross-kernel dependency gap. Block 0 decodes gstart; last block writes
// offsets[N] (= its prefix + its block total).
__global__ void scan23(const int* __restrict__ deg, const int* __restrict__ bsum,
                       int* __restrict__ offsets, int N, int nb,
                       const int* __restrict__ genc, int* __restrict__ gstart) {
  __shared__ int s[256];
  __shared__ int sprefix;
  int t = threadIdx.x;
  int b = blockIdx.x;
  // cooperative prefix = sum(bsum[0..b-1])
  int pre = 0;
  for (int i = t; i < b; i += 256) pre += bsum[i];
  s[t] = pre;
  __syncthreads();
  for (int off = 128; off > 0; off >>= 1) {
    if (t < off) s[t] += s[t + off];
    __syncthreads();
  }
  if (t == 0) sprefix = s[0];
  __syncthreads();
  int prefix = sprefix;
  __syncthreads();                    // s[] reused below
  // local inclusive scan of this block's 256 deg values
  int n = b * 256 + t;
  int v = (n < N) ? deg[n] : 0;
  s[t] = v;
  __syncthreads();
  for (int off = 1; off < 256; off <<= 1) {
    int add = (t >= off) ? s[t - off] : 0;
    __syncthreads();
    s[t] += add;
    __syncthreads();
  }
  if (n < N) offsets[n] = prefix + s[t] - v;  // exclusive
  if (b == nb - 1 && t == 255) offsets[N] = prefix + s[255];
  if (b == 0 && t == 0) {
    // decode group starts; suffix-min so empty groups collapse to 0-length
    int nxt = N;
    gstart[NG] = N;
    for (int g = NG - 1; g >= 0; --g) {
      int st = N - genc[g];
      if (st > nxt) st = nxt;
      gstart[g] = st;
      nxt = st;
    }
  }
}

// ---------- K4: fill CSR with (edge, src) pairs; consumes deg ----------
__global__ void fill_csr(const int* __restrict__ ei, int* __restrict__ deg,
                         const int* __restrict__ offsets, int2* __restrict__ csr2, int E) {
  int e = blockIdx.x * 256 + threadIdx.x;
  if (e >= E) return;
  int d = ei[E + e];
  int pos = atomicSub(&deg[d], 1) - 1;
  csr2[offsets[d] + pos] = make_int2(e, ei[e]);
}

// ---------- K5: FUSED per-node attention + defer-max online softmax + agg ----------
// ONE WAVE per node, ONE 64-thread BLOCK per wave, grid = N (R12/R13 lessons:
// independent 1-wave blocks avoid lifetime coupling AND let the HW scheduler
// load-balance Poisson-variable node degrees dynamically). Lane l owns channels
// (2l,2l+1) packed f32x2; neighbor AND self-loop xl in bf16 from xlh (4B/lane).
// Head = 8 lanes -> 3-stage DPP. Self-loop (ea fill 'mean') merged via
// linearity. Logits in log2 space (att pre-scaled by log2e).
__global__ void __launch_bounds__(64) fused_node(
    const int* __restrict__ offsets, const int2* __restrict__ csr2,
    const float* __restrict__ ea, const unsigned* __restrict__ xlh,
    const float* __restrict__ xr,
    const float* __restrict__ We, const float* __restrict__ att,
    const float* __restrict__ x, const float* __restrict__ bias,
    float* __restrict__ out, int N) {
  int l = threadIdx.x;
  long n = blockIdx.x;
  if (n >= N) return;
  int c0 = l * 2;
  // We pairs, k-major: wx[kp] = (We[2kp][c0], We[2kp+1][c0]); wy for c0+1.
  f32x2 wx[8], wy[8];
  #pragma unroll
  for (int kp = 0; kp < 8; ++kp) {
    wx[kp] = (f32x2){We[(2 * kp) * HC + c0],     We[(2 * kp + 1) * HC + c0]};
    wy[kp] = (f32x2){We[(2 * kp) * HC + c0 + 1], We[(2 * kp + 1) * HC + c0 + 1]};
  }
  f32x2 av2 = {att[c0] * LOG2E, att[c0 + 1] * LOG2E};
  f32x2 av08 = 0.8f * av2, av02 = 0.2f * av2;
  f32x2 xl2 = unpack_bf16x2(xlh[n * (HC / 2) + l]);   // self-loop xl (bf16)
  f32x2 xr2 = *(const f32x2*)(xr + n * HC + c0);
  f32x2 seedA = {xr2.x, 0.f};   // dot-accumulator seeds (fold +xr into hadd)
  f32x2 seedB = {xr2.y, 0.f};
  int j0 = offsets[n], j1 = offsets[n + 1];

  float m = -INFINITY;          // running max (log2), uniform per 8-lane head
  float den = 0.f;
  f32x2 acc = {0.f, 0.f};
  f32x2 eesum = {0.f, 0.f};     // per-channel sum of (eev + xr); adjusted at end

  auto edge_update = [&](int e, f32x2 xls) {
    const float4* eap = (const float4*)(ea + (long)e * EDIM);
    float4 a0 = eap[0], a1 = eap[1], a2 = eap[2], a3 = eap[3];
    f32x2 dA = seedA, dB = seedB;
    f32x2 e01;
    e01 = (f32x2){a0.x, a0.y};
    dA = __builtin_elementwise_fma(e01, wx[0], dA);
    dB = __builtin_elementwise_fma(e01, wy[0], dB);
    e01 = (f32x2){a0.z, a0.w};
    dA = __builtin_elementwise_fma(e01, wx[1], dA);
    dB = __builtin_elementwise_fma(e01, wy[1], dB);
    e01 = (f32x2){a1.x, a1.y};
    dA = __builtin_elementwise_fma(e01, wx[2], dA);
    dB = __builtin_elementwise_fma(e01, wy[2], dB);
    e01 = (f32x2){a1.z, a1.w};
    dA = __builtin_elementwise_fma(e01, wx[3], dA);
    dB = __builtin_elementwise_fma(e01, wy[3], dB);
    e01 = (f32x2){a2.x, a2.y};
    dA = __builtin_elementwise_fma(e01, wx[4], dA);
    dB = __builtin_elementwise_fma(e01, wy[4], dB);
    e01 = (f32x2){a2.z, a2.w};
    dA = __builtin_elementwise_fma(e01, wx[5], dA);
    dB = __builtin_elementwise_fma(e01, wy[5], dB);
    e01 = (f32x2){a3.x, a3.y};
    dA = __builtin_elementwise_fma(e01, wx[6], dA);
    dB = __builtin_elementwise_fma(e01, wy[6], dB);
    e01 = (f32x2){a3.z, a3.w};
    dA = __builtin_elementwise_fma(e01, wx[7], dA);
    dB = __builtin_elementwise_fma(e01, wy[7], dB);
    f32x2 mm = {dA.x + dA.y, dB.x + dB.y};   // = eev + xr (per channel)
    eesum += mm;
    mm += xls;
    f32x2 tt = __builtin_elementwise_fma(
        av08, __builtin_elementwise_max(mm, (f32x2)0.f), av02 * mm);
    float p = head8_sum(tt.x + tt.y);  // head logit, uniform in 8-lane group
    if (p > m + 11.5f) {               // rare: new max grew past threshold
      float sc = exp2f(m - p);
      acc = acc * sc + xls;
      den = fmaf(den, sc, 1.f);
      m = p;
    } else {                           // common: single exp2, no rescale
      float w = exp2f(p - m);
      acc = __builtin_elementwise_fma((f32x2)w, xls, acc);
      den += w;
    }
  };

  auto gath = [&](int s) -> f32x2 {
    return unpack_bf16x2(xlh[(long)s * (HC / 2) + l]);   // 4B/lane bf16 gather
  };
  auto edge_single = [&](int jj) {
    int2 es = csr2[jj];
    int e = __builtin_amdgcn_readfirstlane(es.x);
    int s = __builtin_amdgcn_readfirstlane(es.y);
    edge_update(e, gath(s));
  };

  int j = j0;
  if ((j & 1) && j < j1) { edge_single(j); ++j; }   // peel to 16B alignment
  for (; j + 1 < j1; j += 2) {
    int4 q = *(const int4*)(csr2 + j);  // two (edge,src) pairs, one dwordx4
    int e0 = __builtin_amdgcn_readfirstlane(q.x);
    int s0 = __builtin_amdgcn_readfirstlane(q.y);
    int e1 = __builtin_amdgcn_readfirstlane(q.z);
    int s1 = __builtin_amdgcn_readfirstlane(q.w);
    f32x2 xls0 = gath(s0);
    f32x2 xls1 = gath(s1);
    edge_update(e0, xls0);
    edge_update(e1, xls1);
  }
  if (j < j1) edge_single(j);

  // ---- self-loop ----
  int dg = j1 - j0;
  f32x2 ee = (dg > 0) ? (eesum * (1.f / (float)dg) - xr2) : (f32x2)0.f;
  f32x2 mm = xl2 + xr2 + ee;
  f32x2 tt = __builtin_elementwise_fma(
      av08, __builtin_elementwise_max(mm, (f32x2)0.f), av02 * mm);
  float p = head8_sum(tt.x + tt.y);
  if (p > m) {
    float sc = exp2f(m - p);
    acc = acc * sc + xl2;
    den = fmaf(den, sc, 1.f);
  } else {
    float w = exp2f(p - m);
    acc = __builtin_elementwise_fma((f32x2)w, xl2, acc);
    den += w;
  }

  f32x2 b2 = *(const f32x2*)(bias + c0);
  f32x2 x2 = *(const f32x2*)(x + n * HC + c0);
  f32x2 o = acc * (1.f / den) + b2 + x2;
  *(f32x2*)(out + n * HC + c0) = o;
}

// ---------- K6: GraphNorm segment sums (grid-parallel over group slices) ----------
#define GN_SLICES 32
__global__ void __launch_bounds__(128) gn_stats(
    const float* __restrict__ out, const int* __restrict__ gstart,
    float* __restrict__ gsum, float* __restrict__ gsq) {
  int g = blockIdx.x >> 5;
  int slice = blockIdx.x & 31;
  int s0 = gstart[g], s1 = gstart[g + 1];
  int cnt = s1 - s0;
  if (cnt <= 0) return;
  int chunk = (cnt + GN_SLICES - 1) / GN_SLICES;
  int lo = s0 + slice * chunk;
  int hi = lo + chunk; if (hi > s1) hi = s1;
  if (lo >= hi) return;
  int ch = threadIdx.x;
  float sum = 0.f, sq = 0.f;
  for (int nrow = lo; nrow < hi; ++nrow) {
    float v = out[(long)nrow * HC + ch];
    sum += v; sq += v * v;
  }
  atomicAdd(&gsum[g * HC + ch], sum);
  atomicAdd(&gsq[g * HC + ch], sq);
}

// ---------- K7: normalize + affine + ELU, with inline mean/istd (fused finalize) ----
__global__ void gn_apply(float* __restrict__ out, const int* __restrict__ batch,
                         const float* __restrict__ gsum, const float* __restrict__ gsq,
                         const int* __restrict__ gstart, const float* __restrict__ gms,
                         const float* __restrict__ gnw, const float* __restrict__ gnb, int N) {
  long i = (long)blockIdx.x * 256 + threadIdx.x;     // float4 index
  if (i >= (long)N * 32) return;
  int c4 = (int)(i & 31);
  long n = i >> 5;
  int g = batch[n];
  float cnt = (float)(gstart[g + 1] - gstart[g]);
  if (cnt < 1.f) cnt = 1.f;
  float ic = 1.f / cnt;
  float4 su = ((const float4*)gsum)[g * 32 + c4];
  float4 sq = ((const float4*)gsq)[g * 32 + c4];
  float4 ms4 = ((const float4*)gms)[c4];
  float4 v = ((const float4*)out)[i];
  float4 w  = ((const float4*)gnw)[c4];
  float4 b  = ((const float4*)gnb)[c4];
  float4 o;
  #pragma unroll
  for (int k = 0; k < 4; ++k) {
    float mean = (&su.x)[k] * ic;
    float c = (&ms4.x)[k] * mean;                       // subtracted constant
    float var = (&sq.x)[k] * ic - 2.f * c * mean + c * c;
    float istd = rsqrtf(var + GEPS);
    float oo = fmaf((&w.x)[k] * ((&v.x)[k] - c), istd, (&b.x)[k]);
    (&o.x)[k] = oo > 0.f ? oo : expm1f(oo);
  }
  ((float4*)out)[i] = o;
}

extern "C" void kernel_launch(void* const* d_in, const int* in_sizes, int n_in,
                              void* d_out, int out_size, void* d_ws, size_t ws_size,
                              hipStream_t stream) {
  const float* x    = (const float*)d_in[0];
  const int*   ei   = (const int*)d_in[1];
  const float* ea   = (const float*)d_in[2];
  const int*   batch= (const int*)d_in[3];
  const float* Wl   = (const float*)d_in[4];
  const float* bl   = (const float*)d_in[5];
  const float* Wr   = (const float*)d_in[6];
  const float* br   = (const float*)d_in[7];
  const float* We   = (const float*)d_in[8];
  const float* att  = (const float*)d_in[9];
  const float* bias = (const float*)d_in[10];
  const float* gnw  = (const float*)d_in[11];
  const float* gnb  = (const float*)d_in[12];
  const float* gms  = (const float*)d_in[13];
  int N = in_sizes[0] / HC;
  int E = in_sizes[2] / EDIM;
  float* out = (float*)d_out;
  (void)n_in; (void)out_size; (void)ws_size;

  // ---- workspace carve-up (4-byte words, 16B aligned blocks) ----
  float* wsf = (float*)d_ws;
  size_t off = 0;
  auto alloc = [&](size_t words) -> float* {
    float* p = wsf + off;
    off += (words + 3) & ~(size_t)3;
    return p;
  };
  int*      deg     = (int*)alloc(N);
  float*    gsum    = alloc(NG * HC);
  float*    gsq     = alloc(NG * HC);
  int*      genc    = (int*)alloc(NG);
  size_t zero_words = off;                 // everything above starts at 0
  int*      gstart  = (int*)alloc(NG + 1);
  int*      bsum    = (int*)alloc(256);
  int*      offsets = (int*)alloc((size_t)N + 1);
  float*    xr      = alloc((size_t)N * HC);
  unsigned* xlh     = (unsigned*)alloc((size_t)N * (HC / 2));
  int2*     csr2    = (int2*)alloc((size_t)E * 2 + 8);

  int nb = (N + 255) / 256;   // scan blocks (<=256 by construction for N<=65536)
  int nbG = (N + GEMM_ROWS - 1) / GEMM_ROWS;
  int nbC = (E + 255) / 256;

  zero_k<<<(unsigned)((zero_words + 255) / 256), 256, 0, stream>>>(wsf, zero_words);
  phase1<<<nbG + nbC, 256, 0, stream>>>(x, Wl, bl, Wr, br, xr, xlh,
                                        ei, deg, batch, genc, nbG, E, N);
  scan1<<<nb, 256, 0, stream>>>(deg, bsum, N);
  scan23<<<nb, 256, 0, stream>>>(deg, bsum, offsets, N, nb, genc, gstart);
  fill_csr<<<(E + 255) / 256, 256, 0, stream>>>(ei, deg, offsets, csr2, E);
  fused_node<<<N, 64, 0, stream>>>(offsets, csr2, ea, xlh, xr, We, att, x, bias, out, N);
  gn_stats<<<NG * GN_SLICES, 128, 0, stream>>>(out, gstart, gsum, gsq);
  {
    long tot = (long)N * 32;
    gn_apply<<<(unsigned)((tot + 255) / 256), 256, 0, stream>>>(out, batch, gsum, gsq, gstart, gms, gnw, gnb, N);
  }
}

// Round 18
// 278.098 us; speedup vs baseline: 1.3642x; 1.1505x over previous
//
#include <hip/hip_runtime.h>

#define HC 128          // H*C = output dim
#define HEADS 8
#define EDIM 16
#define NG 8
#define GEPS 1e-5f
#define LOG2E 1.44269504f

typedef float f32x2 __attribute__((ext_vector_type(2)));

// ---------- bf16x2 pack/unpack (round-to-nearest-even) ----------
__device__ __forceinline__ unsigned pack_bf16x2(float a, float b) {
  unsigned ua = __float_as_uint(a), ub = __float_as_uint(b);
  ua = (ua + 0x7fffu + ((ua >> 16) & 1u)) >> 16;
  ub = (ub + 0x7fffu + ((ub >> 16) & 1u)) >> 16;
  return ua | (ub << 16);
}
__device__ __forceinline__ f32x2 unpack_bf16x2(unsigned u) {
  return (f32x2){__uint_as_float(u << 16), __uint_as_float(u & 0xffff0000u)};
}

// ---------- 8-lane (head) sum via DPP: half_mirror + quad_perm xor2/xor1 ----------
__device__ __forceinline__ float head8_sum(float p) {
  int t;
  t = __builtin_amdgcn_update_dpp(0, __float_as_int(p), 0x141, 0xF, 0xF, true); // row_half_mirror
  p += __int_as_float(t);
  t = __builtin_amdgcn_update_dpp(0, __float_as_int(p), 0x4E, 0xF, 0xF, true);  // quad_perm [2,3,0,1]
  p += __int_as_float(t);
  t = __builtin_amdgcn_update_dpp(0, __float_as_int(p), 0xB1, 0xF, 0xF, true);  // quad_perm [1,0,3,2]
  p += __int_as_float(t);
  return p;
}

// ---------- K0: zero scratch ----------
__global__ void zero_k(float* __restrict__ p, size_t nwords) {
  size_t i = (size_t)blockIdx.x * 256 + threadIdx.x;
  if (i < nwords) p[i] = 0.f;
}

// ---------- K1: MERGED phase1 -- GEMM role + edge-count role ----------
// Blocks [0, nbG): LDS-tiled GEMM  xr = x@Wr+br (fp32), xlh = bf16(x@Wl+bl).
// 64 rows/block, 8 rows/thread (GEMM is ds_read-bound; 8-row tile amortizes W
// reads). Blocks [nbG, nbG+nbC): degree count + group-boundary marks, hidden
// under the GEMM (independent work; zero_k must precede).
#define GEMM_ROWS 64
__global__ void __launch_bounds__(256) phase1(
    const float* __restrict__ x,
    const float* __restrict__ Wl, const float* __restrict__ bl,
    const float* __restrict__ Wr, const float* __restrict__ br,
    float* __restrict__ xr, unsigned* __restrict__ xlh,
    const int* __restrict__ ei, int* __restrict__ deg,
    const int* __restrict__ batch, int* __restrict__ genc,
    int nbG, int E, int N) {
  __shared__ float4 WL[32][32];        // [k within chunk][col float4 group] 16KB
  __shared__ float4 WR[32][32];        // 16KB
  __shared__ float4 XS[GEMM_ROWS][8];  // [local row][k4 within chunk] 8KB
  int b = blockIdx.x;
  int t = threadIdx.x;
  if (b >= nbG) {
    // ---- edge-count role ----
    int e = (b - nbG) * 256 + t;
    if (e >= E) return;
    atomicAdd(&deg[ei[E + e]], 1);
    if (e < N && (e == 0 || batch[e] != batch[e - 1])) {
      // encode start index i as (N - i) so zero-init means "empty group"
      atomicMax(&genc[batch[e]], N - e);
    }
    return;
  }
  // ---- GEMM role ----
  int cg = t & 31;                // col float4 group (0..31)
  int rt = t >> 5;                // row-thread (0..7), owns rows rt*8..rt*8+7
  int row0 = b * GEMM_ROWS;
  float4 bl4 = ((const float4*)bl)[cg];
  float4 br4 = ((const float4*)br)[cg];
  float4 accl[8], accr[8];
  #pragma unroll
  for (int r = 0; r < 8; ++r) { accl[r] = bl4; accr[r] = br4; }
  const float4* Wl4 = (const float4*)Wl;
  const float4* Wr4 = (const float4*)Wr;
  const float4* x4  = (const float4*)x;
  for (int kc = 0; kc < 4; ++kc) {
    __syncthreads();              // previous chunk fully consumed
    #pragma unroll
    for (int i = 0; i < 4; ++i) {
      int idx = t + i * 256;      // 0..1023
      int kr = idx >> 5, gg = idx & 31;
      WL[kr][gg] = Wl4[(kc * 32 + kr) * 32 + gg];
      WR[kr][gg] = Wr4[(kc * 32 + kr) * 32 + gg];
    }
    #pragma unroll
    for (int i = 0; i < 2; ++i) {
      int idx = t + i * 256;      // 0..511: 64 rows x 8 k4
      int srow = idx >> 3, sk4 = idx & 7;
      long sgrow = row0 + srow;
      XS[srow][sk4] = (sgrow < N) ? x4[sgrow * 32 + kc * 8 + sk4]
                                  : make_float4(0.f, 0.f, 0.f, 0.f);
    }
    __syncthreads();
    #pragma unroll
    for (int k4 = 0; k4 < 8; ++k4) {
      float4 xv[8];
      #pragma unroll
      for (int r = 0; r < 8; ++r) xv[r] = XS[rt * 8 + r][k4];
      #pragma unroll
      for (int kk = 0; kk < 4; ++kk) {
        float4 wl = WL[k4 * 4 + kk][cg];
        float4 wr = WR[k4 * 4 + kk][cg];
        #pragma unroll
        for (int r = 0; r < 8; ++r) {
          float xs = (&xv[r].x)[kk];
          accl[r].x = fmaf(xs, wl.x, accl[r].x);
          accl[r].y = fmaf(xs, wl.y, accl[r].y);
          accl[r].z = fmaf(xs, wl.z, accl[r].z);
          accl[r].w = fmaf(xs, wl.w, accl[r].w);
          accr[r].x = fmaf(xs, wr.x, accr[r].x);
          accr[r].y = fmaf(xs, wr.y, accr[r].y);
          accr[r].z = fmaf(xs, wr.z, accr[r].z);
          accr[r].w = fmaf(xs, wr.w, accr[r].w);
        }
      }
    }
  }
  #pragma unroll
  for (int r = 0; r < 8; ++r) {
    long row = row0 + rt * 8 + r;
    if (row < N) {
      ((float4*)(xr + row * HC))[cg] = accr[r];
      uint2 h;
      h.x = pack_bf16x2(accl[r].x, accl[r].y);
      h.y = pack_bf16x2(accl[r].z, accl[r].w);
      ((uint2*)(xlh + row * (HC / 2)))[cg] = h;
    }
  }
}

// ---------- K2: per-block sums of deg ----------
__global__ void scan1(const int* __restrict__ deg, int* __restrict__ bsum, int N) {
  __shared__ int s[256];
  int t = threadIdx.x;
  int n = blockIdx.x * 256 + t;
  s[t] = (n < N) ? deg[n] : 0;
  __syncthreads();
  for (int off = 128; off > 0; off >>= 1) {
    if (t < off) s[t] += s[t + off];
    __syncthreads();
  }
  if (t == 0) bsum[blockIdx.x] = s[0];
}

// ---------- K3: MERGED scan2+scan3 -- each block self-computes its prefix ----------
__global__ void scan23(const int* __restrict__ deg, const int* __restrict__ bsum,
                       int* __restrict__ offsets, int N, int nb,
                       const int* __restrict__ genc, int* __restrict__ gstart) {
  __shared__ int s[256];
  __shared__ int sprefix;
  int t = threadIdx.x;
  int b = blockIdx.x;
  // cooperative prefix = sum(bsum[0..b-1])
  int pre = 0;
  for (int i = t; i < b; i += 256) pre += bsum[i];
  s[t] = pre;
  __syncthreads();
  for (int off = 128; off > 0; off >>= 1) {
    if (t < off) s[t] += s[t + off];
    __syncthreads();
  }
  if (t == 0) sprefix = s[0];
  __syncthreads();
  int prefix = sprefix;
  __syncthreads();                    // s[] reused below
  // local inclusive scan of this block's 256 deg values
  int n = b * 256 + t;
  int v = (n < N) ? deg[n] : 0;
  s[t] = v;
  __syncthreads();
  for (int off = 1; off < 256; off <<= 1) {
    int add = (t >= off) ? s[t - off] : 0;
    __syncthreads();
    s[t] += add;
    __syncthreads();
  }
  if (n < N) offsets[n] = prefix + s[t] - v;  // exclusive
  if (b == nb - 1 && t == 255) offsets[N] = prefix + s[255];
  if (b == 0 && t == 0) {
    // decode group starts; suffix-min so empty groups collapse to 0-length
    int nxt = N;
    gstart[NG] = N;
    for (int g = NG - 1; g >= 0; --g) {
      int st = N - genc[g];
      if (st > nxt) st = nxt;
      gstart[g] = st;
      nxt = st;
    }
  }
}

// ---------- K4: fill CSR with (edge, src) pairs; consumes deg ----------
__global__ void fill_csr(const int* __restrict__ ei, int* __restrict__ deg,
                         const int* __restrict__ offsets, int2* __restrict__ csr2, int E) {
  int e = blockIdx.x * 256 + threadIdx.x;
  if (e >= E) return;
  int d = ei[E + e];
  int pos = atomicSub(&deg[d], 1) - 1;
  csr2[offsets[d] + pos] = make_int2(e, ei[e]);
}

// ---------- K5: FUSED per-node attention + defer-max online softmax + agg ----------
// ONE WAVE per node, ONE 64-thread BLOCK per wave, grid = N (R12/R13 lessons:
// independent 1-wave blocks avoid lifetime coupling AND let the HW scheduler
// load-balance Poisson-variable node degrees dynamically). Lane l owns channels
// (2l,2l+1) packed f32x2; neighbor AND self-loop xl in bf16 from xlh (4B/lane).
// Head = 8 lanes -> 3-stage DPP. Self-loop (ea fill 'mean') merged via
// linearity. Logits in log2 space (att pre-scaled by log2e).
__global__ void __launch_bounds__(64) fused_node(
    const int* __restrict__ offsets, const int2* __restrict__ csr2,
    const float* __restrict__ ea, const unsigned* __restrict__ xlh,
    const float* __restrict__ xr,
    const float* __restrict__ We, const float* __restrict__ att,
    const float* __restrict__ x, const float* __restrict__ bias,
    float* __restrict__ out, int N) {
  int l = threadIdx.x;
  long n = blockIdx.x;
  if (n >= N) return;
  int c0 = l * 2;
  // We pairs, k-major: wx[kp] = (We[2kp][c0], We[2kp+1][c0]); wy for c0+1.
  f32x2 wx[8], wy[8];
  #pragma unroll
  for (int kp = 0; kp < 8; ++kp) {
    wx[kp] = (f32x2){We[(2 * kp) * HC + c0],     We[(2 * kp + 1) * HC + c0]};
    wy[kp] = (f32x2){We[(2 * kp) * HC + c0 + 1], We[(2 * kp + 1) * HC + c0 + 1]};
  }
  f32x2 av2 = {att[c0] * LOG2E, att[c0 + 1] * LOG2E};
  f32x2 av08 = 0.8f * av2, av02 = 0.2f * av2;
  f32x2 xl2 = unpack_bf16x2(xlh[n * (HC / 2) + l]);   // self-loop xl (bf16)
  f32x2 xr2 = *(const f32x2*)(xr + n * HC + c0);
  f32x2 seedA = {xr2.x, 0.f};   // dot-accumulator seeds (fold +xr into hadd)
  f32x2 seedB = {xr2.y, 0.f};
  int j0 = offsets[n], j1 = offsets[n + 1];

  float m = -INFINITY;          // running max (log2), uniform per 8-lane head
  float den = 0.f;
  f32x2 acc = {0.f, 0.f};
  f32x2 eesum = {0.f, 0.f};     // per-channel sum of (eev + xr); adjusted at end

  auto edge_update = [&](int e, f32x2 xls) {
    const float4* eap = (const float4*)(ea + (long)e * EDIM);
    float4 a0 = eap[0], a1 = eap[1], a2 = eap[2], a3 = eap[3];
    f32x2 dA = seedA, dB = seedB;
    f32x2 e01;
    e01 = (f32x2){a0.x, a0.y};
    dA = __builtin_elementwise_fma(e01, wx[0], dA);
    dB = __builtin_elementwise_fma(e01, wy[0], dB);
    e01 = (f32x2){a0.z, a0.w};
    dA = __builtin_elementwise_fma(e01, wx[1], dA);
    dB = __builtin_elementwise_fma(e01, wy[1], dB);
    e01 = (f32x2){a1.x, a1.y};
    dA = __builtin_elementwise_fma(e01, wx[2], dA);
    dB = __builtin_elementwise_fma(e01, wy[2], dB);
    e01 = (f32x2){a1.z, a1.w};
    dA = __builtin_elementwise_fma(e01, wx[3], dA);
    dB = __builtin_elementwise_fma(e01, wy[3], dB);
    e01 = (f32x2){a2.x, a2.y};
    dA = __builtin_elementwise_fma(e01, wx[4], dA);
    dB = __builtin_elementwise_fma(e01, wy[4], dB);
    e01 = (f32x2){a2.z, a2.w};
    dA = __builtin_elementwise_fma(e01, wx[5], dA);
    dB = __builtin_elementwise_fma(e01, wy[5], dB);
    e01 = (f32x2){a3.x, a3.y};
    dA = __builtin_elementwise_fma(e01, wx[6], dA);
    dB = __builtin_elementwise_fma(e01, wy[6], dB);
    e01 = (f32x2){a3.z, a3.w};
    dA = __builtin_elementwise_fma(e01, wx[7], dA);
    dB = __builtin_elementwise_fma(e01, wy[7], dB);
    f32x2 mm = {dA.x + dA.y, dB.x + dB.y};   // = eev + xr (per channel)
    eesum += mm;
    mm += xls;
    f32x2 tt = __builtin_elementwise_fma(
        av08, __builtin_elementwise_max(mm, (f32x2)0.f), av02 * mm);
    float p = head8_sum(tt.x + tt.y);  // head logit, uniform in 8-lane group
    if (p > m + 11.5f) {               // rare: new max grew past threshold
      float sc = exp2f(m - p);
      acc = acc * sc + xls;
      den = fmaf(den, sc, 1.f);
      m = p;
    } else {                           // common: single exp2, no rescale
      float w = exp2f(p - m);
      acc = __builtin_elementwise_fma((f32x2)w, xls, acc);
      den += w;
    }
  };

  auto gath = [&](int s) -> f32x2 {
    return unpack_bf16x2(xlh[(long)s * (HC / 2) + l]);   // 4B/lane bf16 gather
  };
  auto edge_single = [&](int jj) {
    int2 es = csr2[jj];
    int e = __builtin_amdgcn_readfirstlane(es.x);
    int s = __builtin_amdgcn_readfirstlane(es.y);
    edge_update(e, gath(s));
  };

  int j = j0;
  if ((j & 1) && j < j1) { edge_single(j); ++j; }   // peel to 16B alignment
  for (; j + 1 < j1; j += 2) {
    int4 q = *(const int4*)(csr2 + j);  // two (edge,src) pairs, one dwordx4
    int e0 = __builtin_amdgcn_readfirstlane(q.x);
    int s0 = __builtin_amdgcn_readfirstlane(q.y);
    int e1 = __builtin_amdgcn_readfirstlane(q.z);
    int s1 = __builtin_amdgcn_readfirstlane(q.w);
    f32x2 xls0 = gath(s0);
    f32x2 xls1 = gath(s1);
    edge_update(e0, xls0);
    edge_update(e1, xls1);
  }
  if (j < j1) edge_single(j);

  // ---- self-loop ----
  int dg = j1 - j0;
  f32x2 ee = (dg > 0) ? (eesum * (1.f / (float)dg) - xr2) : (f32x2)0.f;
  f32x2 mm = xl2 + xr2 + ee;
  f32x2 tt = __builtin_elementwise_fma(
      av08, __builtin_elementwise_max(mm, (f32x2)0.f), av02 * mm);
  float p = head8_sum(tt.x + tt.y);
  if (p > m) {
    float sc = exp2f(m - p);
    acc = acc * sc + xl2;
    den = fmaf(den, sc, 1.f);
  } else {
    float w = exp2f(p - m);
    acc = __builtin_elementwise_fma((f32x2)w, xl2, acc);
    den += w;
  }

  f32x2 b2 = *(const f32x2*)(bias + c0);
  f32x2 x2 = *(const f32x2*)(x + n * HC + c0);
  f32x2 o = acc * (1.f / den) + b2 + x2;
  *(f32x2*)(out + n * HC + c0) = o;
}

// ---------- K6: GraphNorm segment sums (grid-parallel over group slices) ----------
// GN_SLICES=256 (R17 postmortem: 32 slices = only 32K threads, latency-bound
// ~2-3x its streaming floor; 2048 blocks saturate. Atomics stay tiny: 512K
// over an 8KB L2-resident region).
#define GN_SLICES 256
__global__ void __launch_bounds__(128) gn_stats(
    const float* __restrict__ out, const int* __restrict__ gstart,
    float* __restrict__ gsum, float* __restrict__ gsq) {
  int g = blockIdx.x >> 8;
  int slice = blockIdx.x & 255;
  int s0 = gstart[g], s1 = gstart[g + 1];
  int cnt = s1 - s0;
  if (cnt <= 0) return;
  int chunk = (cnt + GN_SLICES - 1) / GN_SLICES;
  int lo = s0 + slice * chunk;
  int hi = lo + chunk; if (hi > s1) hi = s1;
  if (lo >= hi) return;
  int ch = threadIdx.x;
  float sum = 0.f, sq = 0.f;
  for (int nrow = lo; nrow < hi; ++nrow) {
    float v = out[(long)nrow * HC + ch];
    sum += v; sq += v * v;
  }
  atomicAdd(&gsum[g * HC + ch], sum);
  atomicAdd(&gsq[g * HC + ch], sq);
}

// ---------- K7: normalize + affine + ELU, with inline mean/istd (fused finalize) ----
__global__ void gn_apply(float* __restrict__ out, const int* __restrict__ batch,
                         const float* __restrict__ gsum, const float* __restrict__ gsq,
                         const int* __restrict__ gstart, const float* __restrict__ gms,
                         const float* __restrict__ gnw, const float* __restrict__ gnb, int N) {
  long i = (long)blockIdx.x * 256 + threadIdx.x;     // float4 index
  if (i >= (long)N * 32) return;
  int c4 = (int)(i & 31);
  long n = i >> 5;
  int g = batch[n];
  float cnt = (float)(gstart[g + 1] - gstart[g]);
  if (cnt < 1.f) cnt = 1.f;
  float ic = 1.f / cnt;
  float4 su = ((const float4*)gsum)[g * 32 + c4];
  float4 sq = ((const float4*)gsq)[g * 32 + c4];
  float4 ms4 = ((const float4*)gms)[c4];
  float4 v = ((const float4*)out)[i];
  float4 w  = ((const float4*)gnw)[c4];
  float4 b  = ((const float4*)gnb)[c4];
  float4 o;
  #pragma unroll
  for (int k = 0; k < 4; ++k) {
    float mean = (&su.x)[k] * ic;
    float c = (&ms4.x)[k] * mean;                       // subtracted constant
    float var = (&sq.x)[k] * ic - 2.f * c * mean + c * c;
    float istd = rsqrtf(var + GEPS);
    float oo = fmaf((&w.x)[k] * ((&v.x)[k] - c), istd, (&b.x)[k]);
    (&o.x)[k] = oo > 0.f ? oo : expm1f(oo);
  }
  ((float4*)out)[i] = o;
}

extern "C" void kernel_launch(void* const* d_in, const int* in_sizes, int n_in,
                              void* d_out, int out_size, void* d_ws, size_t ws_size,
                              hipStream_t stream) {
  const float* x    = (const float*)d_in[0];
  const int*   ei   = (const int*)d_in[1];
  const float* ea   = (const float*)d_in[2];
  const int*   batch= (const int*)d_in[3];
  const float* Wl   = (const float*)d_in[4];
  const float* bl   = (const float*)d_in[5];
  const float* Wr   = (const float*)d_in[6];
  const float* br   = (const float*)d_in[7];
  const float* We   = (const float*)d_in[8];
  const float* att  = (const float*)d_in[9];
  const float* bias = (const float*)d_in[10];
  const float* gnw  = (const float*)d_in[11];
  const float* gnb  = (const float*)d_in[12];
  const float* gms  = (const float*)d_in[13];
  int N = in_sizes[0] / HC;
  int E = in_sizes[2] / EDIM;
  float* out = (float*)d_out;
  (void)n_in; (void)out_size; (void)ws_size;

  // ---- workspace carve-up (4-byte words, 16B aligned blocks) ----
  float* wsf = (float*)d_ws;
  size_t off = 0;
  auto alloc = [&](size_t words) -> float* {
    float* p = wsf + off;
    off += (words + 3) & ~(size_t)3;
    return p;
  };
  int*      deg     = (int*)alloc(N);
  float*    gsum    = alloc(NG * HC);
  float*    gsq     = alloc(NG * HC);
  int*      genc    = (int*)alloc(NG);
  size_t zero_words = off;                 // everything above starts at 0
  int*      gstart  = (int*)alloc(NG + 1);
  int*      bsum    = (int*)alloc(256);
  int*      offsets = (int*)alloc((size_t)N + 1);
  float*    xr      = alloc((size_t)N * HC);
  unsigned* xlh     = (unsigned*)alloc((size_t)N * (HC / 2));
  int2*     csr2    = (int2*)alloc((size_t)E * 2 + 8);

  int nb = (N + 255) / 256;   // scan blocks (<=256 by construction for N<=65536)
  int nbG = (N + GEMM_ROWS - 1) / GEMM_ROWS;
  int nbC = (E + 255) / 256;

  zero_k<<<(unsigned)((zero_words + 255) / 256), 256, 0, stream>>>(wsf, zero_words);
  phase1<<<nbG + nbC, 256, 0, stream>>>(x, Wl, bl, Wr, br, xr, xlh,
                                        ei, deg, batch, genc, nbG, E, N);
  scan1<<<nb, 256, 0, stream>>>(deg, bsum, N);
  scan23<<<nb, 256, 0, stream>>>(deg, bsum, offsets, N, nb, genc, gstart);
  fill_csr<<<(E + 255) / 256, 256, 0, stream>>>(ei, deg, offsets, csr2, E);
  fused_node<<<N, 64, 0, stream>>>(offsets, csr2, ea, xlh, xr, We, att, x, bias, out, N);
  gn_stats<<<NG * GN_SLICES, 128, 0, stream>>>(out, gstart, gsum, gsq);
  {
    long tot = (long)N * 32;
    gn_apply<<<(unsigned)((tot + 255) / 256), 256, 0, stream>>>(out, batch, gsum, gsq, gstart, gms, gnw, gnb, N);
  }
}